// Round 1
// baseline (411.010 us; speedup 1.0000x reference)
//
#include <hip/hip_runtime.h>
#include <hip/hip_bf16.h>
#include <cstdint>
#include <cstddef>

#define M_DIM 8192
#define K_DIM 4096
#define N_DIM 4096
#define EPS 1e-5f

typedef __bf16 bf16x8 __attribute__((ext_vector_type(8)));
typedef unsigned short u16x8 __attribute__((ext_vector_type(8)));
typedef float f32x4 __attribute__((ext_vector_type(4)));

// ---------- helpers ----------

__device__ __forceinline__ unsigned short f2bf(float f) {
  unsigned int u = __builtin_bit_cast(unsigned int, f);
  u += 0x7fffu + ((u >> 16) & 1u);   // round-to-nearest-even
  return (unsigned short)(u >> 16);
}

__device__ __forceinline__ float fused_epilogue(float acc, float inv, float shift) {
  // BN affine folded: y = acc*inv + shift, inv = gamma*rsqrt(var+eps), shift = beta - mean*inv
  float y = fmaf(acc, inv, shift);
  float y3 = y * y * y;
  float t = tanhf(0.7978845608f * fmaf(0.044715f, y3, y));
  float ge = 0.5f * y * (1.0f + t);
  return fmaxf(ge, 0.0f);
}

__device__ __forceinline__ void gload_lds16(const void* gsrc, void* ldst) {
  __builtin_amdgcn_global_load_lds(
      (const __attribute__((address_space(1))) void*)gsrc,
      (__attribute__((address_space(3))) void*)ldst,
      16, 0, 0);
}

// ---------- pre-pass: fp32 -> bf16 conversions ----------

__global__ __launch_bounds__(256) void cvt_x_kernel(const float* __restrict__ x,
                                                    unsigned short* __restrict__ xb) {
  size_t i = ((size_t)blockIdx.x * 256 + threadIdx.x) * 8;
  float4 a = *reinterpret_cast<const float4*>(x + i);
  float4 b = *reinterpret_cast<const float4*>(x + i + 4);
  u16x8 o;
  o[0] = f2bf(a.x); o[1] = f2bf(a.y); o[2] = f2bf(a.z); o[3] = f2bf(a.w);
  o[4] = f2bf(b.x); o[5] = f2bf(b.y); o[6] = f2bf(b.z); o[7] = f2bf(b.w);
  *reinterpret_cast<u16x8*>(xb + i) = o;
}

// W [K][N] fp32 -> Wt [N][K] bf16 (transpose + convert)
__global__ __launch_bounds__(256) void cvt_w_transpose(const float* __restrict__ W,
                                                       unsigned short* __restrict__ Wt) {
  __shared__ float tile[32][33];
  const int tx = threadIdx.x & 31;
  const int tg = threadIdx.x >> 5;           // 8 groups, 4 rows each
  const int n0 = blockIdx.x * 32;
  const int k0 = blockIdx.y * 32;
#pragma unroll
  for (int j = 0; j < 4; ++j) {
    int k = tg * 4 + j;
    tile[k][tx] = W[(size_t)(k0 + k) * N_DIM + n0 + tx];
  }
  __syncthreads();
#pragma unroll
  for (int j = 0; j < 4; ++j) {
    int n = tg * 4 + j;
    Wt[(size_t)(n0 + n) * K_DIM + k0 + tx] = f2bf(tile[tx][n]);
  }
}

// ---------- main GEMM: 128x128 tile, 4 waves, 16x16x32 bf16 MFMA ----------
// A [M][K] bf16, Bt [N][K] bf16 (both k-major). Fused BN+GELU+ReLU epilogue.

__global__ __launch_bounds__(256, 2) void gemm_bf16_fused(
    const unsigned short* __restrict__ A,
    const unsigned short* __restrict__ Bt,
    const float* __restrict__ gam, const float* __restrict__ bet,
    const float* __restrict__ mu, const float* __restrict__ var,
    float* __restrict__ C) {
  __shared__ __align__(16) unsigned short As[128 * 32];
  __shared__ __align__(16) unsigned short Bs[128 * 32];

  const int tid = threadIdx.x;
  const int wave = tid >> 6;
  const int lane = tid & 63;
  const int l15 = lane & 15, l4 = lane >> 4;

  // XCD-aware swizzle: 2048 blocks, 2048 % 8 == 0 -> bijective
  const int bid = (int)blockIdx.x;
  const int swz = (bid & 7) * 256 + (bid >> 3);
  const int bx = swz & 31;   // N tile index (32 tiles)
  const int by = swz >> 5;   // M tile index (64 tiles)
  const size_t bm = (size_t)by * 128;
  const size_t bn = (size_t)bx * 128;

  const int wr = wave >> 1, wc = wave & 1;   // wave's 64x64 quadrant

  f32x4 acc[4][4] = {};

  // staging addresses: each wave stages 2 x 1KB chunks (16 rows) for A and B
  const int srow = lane >> 2;            // 0..15
  const int skoff = (lane & 3) * 8;      // k element offset 0,8,16,24

  const unsigned short* aSrc0 = A + (bm + (size_t)(wave * 32 + srow)) * K_DIM + skoff;
  const unsigned short* aSrc1 = A + (bm + (size_t)(wave * 32 + 16 + srow)) * K_DIM + skoff;
  const unsigned short* bSrc0 = Bt + (bn + (size_t)(wave * 32 + srow)) * K_DIM + skoff;
  const unsigned short* bSrc1 = Bt + (bn + (size_t)(wave * 32 + 16 + srow)) * K_DIM + skoff;
  unsigned short* aDst0 = &As[(wave * 2 + 0) * 512];
  unsigned short* aDst1 = &As[(wave * 2 + 1) * 512];
  unsigned short* bDst0 = &Bs[(wave * 2 + 0) * 512];
  unsigned short* bDst1 = &Bs[(wave * 2 + 1) * 512];

  for (int k0 = 0; k0 < K_DIM; k0 += 32) {
    gload_lds16(aSrc0 + k0, aDst0);
    gload_lds16(aSrc1 + k0, aDst1);
    gload_lds16(bSrc0 + k0, bDst0);
    gload_lds16(bSrc1 + k0, bDst1);
    __syncthreads();

    bf16x8 af[4], bfv[4];
#pragma unroll
    for (int mi = 0; mi < 4; ++mi)
      af[mi] = __builtin_bit_cast(bf16x8,
          *reinterpret_cast<const u16x8*>(&As[(wr * 64 + mi * 16 + l15) * 32 + l4 * 8]));
#pragma unroll
    for (int ni = 0; ni < 4; ++ni)
      bfv[ni] = __builtin_bit_cast(bf16x8,
          *reinterpret_cast<const u16x8*>(&Bs[(wc * 64 + ni * 16 + l15) * 32 + l4 * 8]));
#pragma unroll
    for (int mi = 0; mi < 4; ++mi)
#pragma unroll
      for (int ni = 0; ni < 4; ++ni)
        acc[mi][ni] = __builtin_amdgcn_mfma_f32_16x16x32_bf16(af[mi], bfv[ni], acc[mi][ni], 0, 0, 0);
    __syncthreads();
  }

  // epilogue: C/D layout (16x16x32): col = lane&15, row = (lane>>4)*4 + reg
  const int row0 = (int)bm + wr * 64;
  const int col0 = (int)bn + wc * 64;
#pragma unroll
  for (int ni = 0; ni < 4; ++ni) {
    const int col = col0 + ni * 16 + l15;
    const float inv = rsqrtf(var[col] + EPS) * gam[col];
    const float shift = fmaf(-mu[col], inv, bet[col]);
#pragma unroll
    for (int mi = 0; mi < 4; ++mi) {
      const int r0 = row0 + mi * 16 + l4 * 4;
#pragma unroll
      for (int r = 0; r < 4; ++r)
        C[(size_t)(r0 + r) * N_DIM + col] = fused_epilogue(acc[mi][ni][r], inv, shift);
    }
  }
}

// ---------- fallback (only if ws too small): fp32 tiled GEMM ----------

__global__ __launch_bounds__(256) void gemm_f32_fallback(
    const float* __restrict__ A, const float* __restrict__ W,
    const float* __restrict__ gam, const float* __restrict__ bet,
    const float* __restrict__ mu, const float* __restrict__ var,
    float* __restrict__ C) {
  __shared__ float As[16][65];
  __shared__ float Bs[16][65];
  const int tid = threadIdx.x;
  const int tx = tid & 15, ty = tid >> 4;
  const int bn0 = blockIdx.x * 64, bm0 = blockIdx.y * 64;
  float acc[4][4] = {};
  for (int k0 = 0; k0 < K_DIM; k0 += 16) {
#pragma unroll
    for (int j = 0; j < 4; ++j)
      As[tid & 15][(tid >> 4) * 4 + j] =
          A[(size_t)(bm0 + (tid >> 4) * 4 + j) * K_DIM + k0 + (tid & 15)];
#pragma unroll
    for (int j = 0; j < 4; ++j)
      Bs[tid >> 4][(tid & 15) * 4 + j] =
          W[(size_t)(k0 + (tid >> 4)) * N_DIM + bn0 + (tid & 15) * 4 + j];
    __syncthreads();
#pragma unroll
    for (int kk = 0; kk < 16; ++kk) {
      float a_[4], b_[4];
#pragma unroll
      for (int i = 0; i < 4; ++i) a_[i] = As[kk][ty * 4 + i];
#pragma unroll
      for (int j = 0; j < 4; ++j) b_[j] = Bs[kk][tx * 4 + j];
#pragma unroll
      for (int i = 0; i < 4; ++i)
#pragma unroll
        for (int j = 0; j < 4; ++j)
          acc[i][j] = fmaf(a_[i], b_[j], acc[i][j]);
    }
    __syncthreads();
  }
#pragma unroll
  for (int j = 0; j < 4; ++j) {
    const int col = bn0 + tx * 4 + j;
    const float inv = rsqrtf(var[col] + EPS) * gam[col];
    const float shift = fmaf(-mu[col], inv, bet[col]);
#pragma unroll
    for (int i = 0; i < 4; ++i)
      C[(size_t)(bm0 + ty * 4 + i) * N_DIM + col] = fused_epilogue(acc[i][j], inv, shift);
  }
}

// ---------- launch ----------

extern "C" void kernel_launch(void* const* d_in, const int* in_sizes, int n_in,
                              void* d_out, int out_size, void* d_ws, size_t ws_size,
                              hipStream_t stream) {
  const float* x  = (const float*)d_in[0];
  const float* w  = (const float*)d_in[1];
  const float* gg = (const float*)d_in[2];
  const float* bb = (const float*)d_in[3];
  const float* mu = (const float*)d_in[4];
  const float* vr = (const float*)d_in[5];
  float* out = (float*)d_out;

  const size_t xb_bytes = (size_t)M_DIM * K_DIM * 2;
  const size_t wt_bytes = (size_t)K_DIM * N_DIM * 2;

  if (ws_size >= xb_bytes + wt_bytes) {
    unsigned short* xb = (unsigned short*)d_ws;
    unsigned short* wt = xb + (size_t)M_DIM * K_DIM;
    cvt_x_kernel<<<dim3((M_DIM * (size_t)K_DIM) / 8 / 256), dim3(256), 0, stream>>>(x, xb);
    cvt_w_transpose<<<dim3(N_DIM / 32, K_DIM / 32), dim3(256), 0, stream>>>(w, wt);
    gemm_bf16_fused<<<dim3((M_DIM / 128) * (N_DIM / 128)), dim3(256), 0, stream>>>(
        xb, wt, gg, bb, mu, vr, out);
  } else {
    gemm_f32_fallback<<<dim3(N_DIM / 64, M_DIM / 64), dim3(256), 0, stream>>>(
        x, w, gg, bb, mu, vr, out);
  }
}

// Round 2
// 303.738 us; speedup vs baseline: 1.3532x; 1.3532x over previous
//
#include <hip/hip_runtime.h>
#include <hip/hip_bf16.h>
#include <cstdint>
#include <cstddef>

#define M_DIM 8192
#define K_DIM 4096
#define N_DIM 4096
#define EPS 1e-5f

typedef __bf16 bf16x8 __attribute__((ext_vector_type(8)));
typedef unsigned short u16x8 __attribute__((ext_vector_type(8)));
typedef float f32x4 __attribute__((ext_vector_type(4)));

// ---------- helpers ----------

__device__ __forceinline__ unsigned short f2bf(float f) {
  unsigned int u = __builtin_bit_cast(unsigned int, f);
  u += 0x7fffu + ((u >> 16) & 1u);   // round-to-nearest-even
  return (unsigned short)(u >> 16);
}

__device__ __forceinline__ float fused_epilogue(float acc, float inv, float shift) {
  float y = fmaf(acc, inv, shift);
  float y3 = y * y * y;
  float t = tanhf(0.7978845608f * fmaf(0.044715f, y3, y));
  float ge = 0.5f * y * (1.0f + t);
  return fmaxf(ge, 0.0f);
}

__device__ __forceinline__ void gload_lds16(const void* gsrc, void* ldst) {
  __builtin_amdgcn_global_load_lds(
      (const __attribute__((address_space(1))) void*)gsrc,
      (__attribute__((address_space(3))) void*)ldst,
      16, 0, 0);
}

// ---------- pre-pass: fp32 -> bf16 conversions ----------

__global__ __launch_bounds__(256) void cvt_x_kernel(const float* __restrict__ x,
                                                    unsigned short* __restrict__ xb) {
  size_t i = ((size_t)blockIdx.x * 256 + threadIdx.x) * 8;
  float4 a = *reinterpret_cast<const float4*>(x + i);
  float4 b = *reinterpret_cast<const float4*>(x + i + 4);
  u16x8 o;
  o[0] = f2bf(a.x); o[1] = f2bf(a.y); o[2] = f2bf(a.z); o[3] = f2bf(a.w);
  o[4] = f2bf(b.x); o[5] = f2bf(b.y); o[6] = f2bf(b.z); o[7] = f2bf(b.w);
  *reinterpret_cast<u16x8*>(xb + i) = o;
}

// W [K][N] fp32 -> Wt [N][K] bf16 (transpose + convert)
__global__ __launch_bounds__(256) void cvt_w_transpose(const float* __restrict__ W,
                                                       unsigned short* __restrict__ Wt) {
  __shared__ float tile[32][33];
  const int tx = threadIdx.x & 31;
  const int tg = threadIdx.x >> 5;
  const int n0 = blockIdx.x * 32;
  const int k0 = blockIdx.y * 32;
#pragma unroll
  for (int j = 0; j < 4; ++j) {
    int k = tg * 4 + j;
    tile[k][tx] = W[(size_t)(k0 + k) * N_DIM + n0 + tx];
  }
  __syncthreads();
#pragma unroll
  for (int j = 0; j < 4; ++j) {
    int n = tg * 4 + j;
    Wt[(size_t)(n0 + n) * K_DIM + k0 + tx] = f2bf(tile[tx][n]);
  }
}

// ---------- main GEMM: 256x256 tile, BK=64, 8 waves, 8-phase schedule ----------
// A [M][K] bf16, Bt [N][K] bf16. LDS: 4 half-tile slots per operand (ring).
// Slot layout: [128 rows][8 col8-groups of 8 bf16], col8' = col8 ^ (row&7) swizzle.

#define STG_A(h, j, PAR, T)                                                        \
  gload_lds16(aS + (size_t)((h)*128 + 64*(j)) * K_DIM + (size_t)((T) + 1) * 64,    \
              &lds[(2*(1-(PAR)) + (h)) * 8192 + (wave + 8*(j)) * 512])

#define STG_B(h, j, PAR, T)                                                        \
  gload_lds16(bS + (size_t)((h)*128 + 64*(j)) * K_DIM + (size_t)((T) + 2) * 64,    \
              &lds[32768 + (2*(PAR) + (h)) * 8192 + (wave + 8*(j)) * 512])

#define MFMA_QUAD(q)                                                               \
  _Pragma("unroll") for (int s = 0; s < 2; ++s)                                    \
  _Pragma("unroll") for (int i = 0; i < 2; ++i)                                    \
  _Pragma("unroll") for (int ni = 0; ni < 4; ++ni)                                 \
    acc[(q)*2 + i][ni] = __builtin_amdgcn_mfma_f32_16x16x32_bf16(                  \
        aq[i][s], bq[ni][s], acc[(q)*2 + i][ni], 0, 0, 0)

#define LOAD_AQ(q)                                                                 \
  _Pragma("unroll") for (int i = 0; i < 2; ++i)                                    \
  _Pragma("unroll") for (int s = 0; s < 2; ++s)                                    \
    aq[i][s] = __builtin_bit_cast(bf16x8,                                          \
        *(const u16x8*)&lds[sa + aro + ((q)*2 + i) * 1024 + xk[s]])

#define PHASE_TAIL(q)                                                              \
  asm volatile("" ::: "memory");                                                   \
  __builtin_amdgcn_s_barrier();                                                    \
  asm volatile("s_waitcnt lgkmcnt(0)" ::: "memory");                               \
  __builtin_amdgcn_s_setprio(1);                                                   \
  MFMA_QUAD(q);                                                                    \
  __builtin_amdgcn_s_setprio(0)

#define KTILE(T, PAR, STA, STB, VM) do {                                           \
  const int sa = (PAR) * 16384 + saW;                                              \
  const int sb = (PAR) * 16384 + sbW;                                              \
  bf16x8 bq[4][2], aq[2][2];                                                       \
  /* phase 0: all B frags + A quad 0; stage A-half0(t+1) */                        \
  _Pragma("unroll") for (int ni = 0; ni < 4; ++ni)                                 \
  _Pragma("unroll") for (int s = 0; s < 2; ++s)                                    \
    bq[ni][s] = __builtin_bit_cast(bf16x8,                                         \
        *(const u16x8*)&lds[sb + bro + ni * 1024 + xk[s]]);                        \
  LOAD_AQ(0);                                                                      \
  if (STA) { STG_A(0, 0, PAR, T); STG_A(0, 1, PAR, T); }                           \
  PHASE_TAIL(0);                                                                   \
  asm volatile("" ::: "memory");                                                   \
  __builtin_amdgcn_s_barrier();                                                    \
  /* phase 1: A quad 1; stage A-half1(t+1) */                                      \
  LOAD_AQ(1);                                                                      \
  if (STA) { STG_A(1, 0, PAR, T); STG_A(1, 1, PAR, T); }                           \
  PHASE_TAIL(1);                                                                   \
  asm volatile("" ::: "memory");                                                   \
  __builtin_amdgcn_s_barrier();                                                    \
  /* phase 2: A quad 2; stage B-half0(t+2) */                                      \
  LOAD_AQ(2);                                                                      \
  if (STB) { STG_B(0, 0, PAR, T); STG_B(0, 1, PAR, T); }                           \
  PHASE_TAIL(2);                                                                   \
  asm volatile("" ::: "memory");                                                   \
  __builtin_amdgcn_s_barrier();                                                    \
  /* phase 3: A quad 3; stage B-half1(t+2); counted vmcnt */                       \
  LOAD_AQ(3);                                                                      \
  if (STB) { STG_B(1, 0, PAR, T); STG_B(1, 1, PAR, T); }                           \
  PHASE_TAIL(3);                                                                   \
  if ((VM) == 4)      asm volatile("s_waitcnt vmcnt(4)" ::: "memory");             \
  else if ((VM) == 0) asm volatile("s_waitcnt vmcnt(0)" ::: "memory");             \
  asm volatile("" ::: "memory");                                                   \
  __builtin_amdgcn_s_barrier();                                                    \
} while (0)

__global__ __launch_bounds__(512, 2) void gemm_bf16_fused(
    const unsigned short* __restrict__ A,
    const unsigned short* __restrict__ Bt,
    const float* __restrict__ gam, const float* __restrict__ bet,
    const float* __restrict__ mu, const float* __restrict__ var,
    float* __restrict__ C) {
  __shared__ __align__(16) unsigned short lds[65536];  // 128 KiB

  const int tid = threadIdx.x;
  const int wave = tid >> 6;
  const int lane = tid & 63;
  const int l15 = lane & 15, l4 = lane >> 4;
  const int wr = wave >> 2, wc = wave & 3;   // 2x4 wave grid; per-wave out 128x64

  // XCD-aware swizzle: 512 blocks, 512 % 8 == 0 -> bijective
  const int bid = (int)blockIdx.x;
  const int swz = (bid & 7) * 64 + (bid >> 3);
  const int bx = swz & 15;                   // 16 N-tiles
  const int by = swz >> 4;                   // 32 M-tiles
  const size_t bm = (size_t)by * 256;
  const size_t bn = (size_t)bx * 256;

  // stage source addresses (pre-swizzled global per lane; LDS dest linear)
  const int lr = lane >> 3, lc = lane & 7;
  const unsigned short* aS = A + (bm + (size_t)(wave * 8 + lr)) * K_DIM + (lc ^ lr) * 8;
  const unsigned short* bS = Bt + (bn + (size_t)(wave * 8 + lr)) * K_DIM + (lc ^ lr) * 8;

  // ds_read fragment offsets (u16 units); col8' = col8 ^ (row&7), row&7 == l15&7
  int xk[2];
  xk[0] = ((l4)     ^ (l15 & 7)) * 8;
  xk[1] = ((l4 | 4) ^ (l15 & 7)) * 8;
  const int aro = l15 * 64;
  const int bro = (wc & 1) * 4096 + l15 * 64;
  const int saW = wr * 8192;
  const int sbW = 32768 + (wc >> 1) * 8192;

  f32x4 acc[8][4] = {};

  // ---- prologue: stage A(0), B(0), B(1); wait K-tile 0 landed ----
  STG_A(0, 0, 1, -1); STG_A(0, 1, 1, -1);   // A(0) half0 -> slots 0
  STG_A(1, 0, 1, -1); STG_A(1, 1, 1, -1);   // A(0) half1 -> slot 1
  STG_B(0, 0, 0, -2); STG_B(0, 1, 0, -2);   // B(0) half0 -> slot 0
  STG_B(1, 0, 0, -2); STG_B(1, 1, 0, -2);   // B(0) half1 -> slot 1
  STG_B(0, 0, 1, -1); STG_B(0, 1, 1, -1);   // B(1) half0 -> slot 2
  STG_B(1, 0, 1, -1); STG_B(1, 1, 1, -1);   // B(1) half1 -> slot 3
  asm volatile("s_waitcnt vmcnt(4)" ::: "memory");  // A(0)+B(0) landed; B(1) in flight
  __builtin_amdgcn_s_barrier();

  // ---- main loop: 64 K-tiles, 2x unrolled for slot parity ----
  for (int t = 0; t < 60; t += 2) {
    KTILE(t,     0, 1, 1, 4);
    KTILE(t + 1, 1, 1, 1, 4);
  }
  KTILE(60, 0, 1, 1, 4);
  KTILE(61, 1, 1, 1, 4);   // stages A(62), B(63)
  KTILE(62, 0, 1, 0, 0);   // stages A(63) only; drain
  KTILE(63, 1, 0, 0, -1);  // no stages, nothing outstanding

  // ---- epilogue: fused BN + GELU + ReLU ----
  const int row0 = (int)bm + wr * 128;
  const int col0 = (int)bn + wc * 64;
#pragma unroll
  for (int ni = 0; ni < 4; ++ni) {
    const int col = col0 + ni * 16 + l15;
    const float inv = rsqrtf(var[col] + EPS) * gam[col];
    const float shift = fmaf(-mu[col], inv, bet[col]);
#pragma unroll
    for (int mi = 0; mi < 8; ++mi) {
      const int r0 = row0 + mi * 16 + l4 * 4;
#pragma unroll
      for (int r = 0; r < 4; ++r)
        C[(size_t)(r0 + r) * N_DIM + col] = fused_epilogue(acc[mi][ni][r], inv, shift);
    }
  }
}

// ---------- fallback (only if ws too small): fp32 tiled GEMM ----------

__global__ __launch_bounds__(256) void gemm_f32_fallback(
    const float* __restrict__ A, const float* __restrict__ W,
    const float* __restrict__ gam, const float* __restrict__ bet,
    const float* __restrict__ mu, const float* __restrict__ var,
    float* __restrict__ C) {
  __shared__ float As[16][65];
  __shared__ float Bs[16][65];
  const int tid = threadIdx.x;
  const int tx = tid & 15, ty = tid >> 4;
  const int bn0 = blockIdx.x * 64, bm0 = blockIdx.y * 64;
  float acc[4][4] = {};
  for (int k0 = 0; k0 < K_DIM; k0 += 16) {
#pragma unroll
    for (int j = 0; j < 4; ++j)
      As[tid & 15][(tid >> 4) * 4 + j] =
          A[(size_t)(bm0 + (tid >> 4) * 4 + j) * K_DIM + k0 + (tid & 15)];
#pragma unroll
    for (int j = 0; j < 4; ++j)
      Bs[tid >> 4][(tid & 15) * 4 + j] =
          W[(size_t)(k0 + (tid >> 4)) * N_DIM + bn0 + (tid & 15) * 4 + j];
    __syncthreads();
#pragma unroll
    for (int kk = 0; kk < 16; ++kk) {
      float a_[4], b_[4];
#pragma unroll
      for (int i = 0; i < 4; ++i) a_[i] = As[kk][ty * 4 + i];
#pragma unroll
      for (int j = 0; j < 4; ++j) b_[j] = Bs[kk][tx * 4 + j];
#pragma unroll
      for (int i = 0; i < 4; ++i)
#pragma unroll
        for (int j = 0; j < 4; ++j)
          acc[i][j] = fmaf(a_[i], b_[j], acc[i][j]);
    }
    __syncthreads();
  }
#pragma unroll
  for (int j = 0; j < 4; ++j) {
    const int col = bn0 + tx * 4 + j;
    const float inv = rsqrtf(var[col] + EPS) * gam[col];
    const float shift = fmaf(-mu[col], inv, bet[col]);
#pragma unroll
    for (int i = 0; i < 4; ++i)
      C[(size_t)(bm0 + ty * 4 + i) * N_DIM + col] = fused_epilogue(acc[i][j], inv, shift);
  }
}

// ---------- launch ----------

extern "C" void kernel_launch(void* const* d_in, const int* in_sizes, int n_in,
                              void* d_out, int out_size, void* d_ws, size_t ws_size,
                              hipStream_t stream) {
  const float* x  = (const float*)d_in[0];
  const float* w  = (const float*)d_in[1];
  const float* gg = (const float*)d_in[2];
  const float* bb = (const float*)d_in[3];
  const float* mu = (const float*)d_in[4];
  const float* vr = (const float*)d_in[5];
  float* out = (float*)d_out;

  const size_t xb_bytes = (size_t)M_DIM * K_DIM * 2;
  const size_t wt_bytes = (size_t)K_DIM * N_DIM * 2;

  if (ws_size >= xb_bytes + wt_bytes) {
    unsigned short* xb = (unsigned short*)d_ws;
    unsigned short* wt = xb + (size_t)M_DIM * K_DIM;
    cvt_x_kernel<<<dim3((M_DIM * (size_t)K_DIM) / 8 / 256), dim3(256), 0, stream>>>(x, xb);
    cvt_w_transpose<<<dim3(N_DIM / 32, K_DIM / 32), dim3(256), 0, stream>>>(w, wt);
    gemm_bf16_fused<<<dim3((M_DIM / 256) * (N_DIM / 256)), dim3(512), 0, stream>>>(
        xb, wt, gg, bb, mu, vr, out);
  } else {
    gemm_f32_fallback<<<dim3(N_DIM / 64, M_DIM / 64), dim3(256), 0, stream>>>(
        x, w, gg, bb, mu, vr, out);
  }
}

// Round 4
// 289.801 us; speedup vs baseline: 1.4183x; 1.0481x over previous
//
#include <hip/hip_runtime.h>
#include <hip/hip_bf16.h>
#include <cstdint>
#include <cstddef>

#define M_DIM 8192
#define K_DIM 4096
#define N_DIM 4096
#define EPS 1e-5f

typedef __bf16 bf16x8 __attribute__((ext_vector_type(8)));
typedef unsigned short u16x8 __attribute__((ext_vector_type(8)));
typedef float f32x4 __attribute__((ext_vector_type(4)));

// ---------- helpers ----------

__device__ __forceinline__ unsigned short f2bf(float f) {
  unsigned int u = __builtin_bit_cast(unsigned int, f);
  u += 0x7fffu + ((u >> 16) & 1u);   // round-to-nearest-even
  return (unsigned short)(u >> 16);
}

// GELU(tanh-approx)+ReLU via identity 0.5y(1+tanh(w)) = y*sigmoid(2w):
// ge = y / (1 + exp2(-c2*z)), z = y + 0.044715 y^3, c2 = 2*0.7978845608*log2(e)
__device__ __forceinline__ float fused_epilogue(float acc, float inv, float shift) {
  float y = fmaf(acc, inv, shift);
  float y2 = y * y;
  float z = fmaf(0.044715f * y2, y, y);
  float e = __builtin_amdgcn_exp2f(-2.3022081f * z);
  float ge = y * __builtin_amdgcn_rcpf(1.0f + e);
  return fmaxf(ge, 0.0f);
}

__device__ __forceinline__ void gload_lds16(const void* gsrc, void* ldst) {
  __builtin_amdgcn_global_load_lds(
      (const __attribute__((address_space(1))) void*)gsrc,
      (__attribute__((address_space(3))) void*)ldst,
      16, 0, 0);
}

// ---------- pre-pass: fp32 -> bf16 conversions ----------

__global__ __launch_bounds__(256) void cvt_x_kernel(const float* __restrict__ x,
                                                    unsigned short* __restrict__ xb) {
  size_t i = ((size_t)blockIdx.x * 256 + threadIdx.x) * 8;
  float4 a = *reinterpret_cast<const float4*>(x + i);
  float4 b = *reinterpret_cast<const float4*>(x + i + 4);
  u16x8 o;
  o[0] = f2bf(a.x); o[1] = f2bf(a.y); o[2] = f2bf(a.z); o[3] = f2bf(a.w);
  o[4] = f2bf(b.x); o[5] = f2bf(b.y); o[6] = f2bf(b.z); o[7] = f2bf(b.w);
  *reinterpret_cast<u16x8*>(xb + i) = o;
}

// W [K][N] fp32 -> Wt [N][K] bf16 (transpose + convert)
__global__ __launch_bounds__(256) void cvt_w_transpose(const float* __restrict__ W,
                                                       unsigned short* __restrict__ Wt) {
  __shared__ float tile[32][33];
  const int tx = threadIdx.x & 31;
  const int tg = threadIdx.x >> 5;
  const int n0 = blockIdx.x * 32;
  const int k0 = blockIdx.y * 32;
#pragma unroll
  for (int j = 0; j < 4; ++j) {
    int k = tg * 4 + j;
    tile[k][tx] = W[(size_t)(k0 + k) * N_DIM + n0 + tx];
  }
  __syncthreads();
#pragma unroll
  for (int j = 0; j < 4; ++j) {
    int n = tg * 4 + j;
    Wt[(size_t)(n0 + n) * K_DIM + k0 + tx] = f2bf(tile[tx][n]);
  }
}

// ---------- main GEMM: 256x256 tile, BK=64, 8 waves, 2-barrier K-tile ----------
// A [M][K] bf16, Bt [N][K] bf16. LDS: 4 half-tile slots per operand (parity ring).
// Swizzle: col8' = col8 ^ (row&7); pre-swizzled global source, linear LDS dest.
//
// Hazard plan per tile t (parity PAR):
//  - STG_A(t+1) -> parity 1-PAR A slots: dead since end-barrier(t-1).  [tile top]
//  - B(t) reads (both k-halves) + A-kh0 reads pre-mid; kh0 MFMAs overlap drains.
//  - mid: lgkmcnt(0)+barrier  => all waves hold B(t) in regs.
//  - STG_B(t+2) -> parity PAR B slots: now safe.  A-kh1 reads (parity PAR A slots,
//    untouched by stages) overlap kh1 MFMAs.
//  - end: lgkmcnt(0); vmcnt(4) keeps B(t+2) in flight; barrier.

#define STG_A(h, j, PAR, T)                                                        \
  gload_lds16(aS + (size_t)((h)*128 + 64*(j)) * K_DIM + (size_t)((T) + 1) * 64,    \
              &lds[(2*(1-(PAR)) + (h)) * 8192 + (wave + 8*(j)) * 512])

#define STG_B(h, j, PAR, T)                                                        \
  gload_lds16(bS + (size_t)((h)*128 + 64*(j)) * K_DIM + (size_t)((T) + 2) * 64,    \
              &lds[32768 + (2*(PAR) + (h)) * 8192 + (wave + 8*(j)) * 512])

#define LDS_FRAG(off) __builtin_bit_cast(bf16x8, *(const u16x8*)&lds[(off)])

#define KTILE(T, PAR, STA, STB, VM) do {                                           \
  const int sa = (PAR) * 16384 + saW;                                              \
  const int sb = (PAR) * 16384 + sbW;                                              \
  if (STA) { STG_A(0,0,PAR,T); STG_A(0,1,PAR,T);                                   \
             STG_A(1,0,PAR,T); STG_A(1,1,PAR,T); }                                 \
  asm volatile("" ::: "memory");                                                   \
  bf16x8 b0[4], b1[4], ak0[8], ak1[8];                                             \
  /* lead reads: enough for first MFMA pair */                                     \
  _Pragma("unroll") for (int ni = 0; ni < 4; ++ni)                                 \
    b0[ni] = LDS_FRAG(sb + bro + ni * 1024 + xk0);                                 \
  ak0[0] = LDS_FRAG(sa + aro + 0 * 1024 + xk0);                                    \
  ak0[1] = LDS_FRAG(sa + aro + 1 * 1024 + xk0);                                    \
  /* trailing reads: drain under kh0 MFMAs */                                      \
  _Pragma("unroll") for (int mi = 2; mi < 8; ++mi)                                 \
    ak0[mi] = LDS_FRAG(sa + aro + mi * 1024 + xk0);                                \
  _Pragma("unroll") for (int ni = 0; ni < 4; ++ni)                                 \
    b1[ni] = LDS_FRAG(sb + bro + ni * 1024 + xk1);                                 \
  __builtin_amdgcn_s_setprio(1);                                                   \
  _Pragma("unroll") for (int mi = 0; mi < 8; ++mi)                                 \
  _Pragma("unroll") for (int ni = 0; ni < 4; ++ni)                                 \
    acc[mi][ni] = __builtin_amdgcn_mfma_f32_16x16x32_bf16(ak0[mi], b0[ni],         \
                                                          acc[mi][ni], 0, 0, 0);   \
  __builtin_amdgcn_s_setprio(0);                                                   \
  asm volatile("s_waitcnt lgkmcnt(0)" ::: "memory");                               \
  __builtin_amdgcn_s_barrier();           /* MID: B(t) fully consumed */           \
  if (STB) { STG_B(0,0,PAR,T); STG_B(0,1,PAR,T);                                   \
             STG_B(1,0,PAR,T); STG_B(1,1,PAR,T); }                                 \
  asm volatile("" ::: "memory");                                                   \
  _Pragma("unroll") for (int mi = 0; mi < 8; ++mi)                                 \
    ak1[mi] = LDS_FRAG(sa + aro + mi * 1024 + xk1);                                \
  __builtin_amdgcn_s_setprio(1);                                                   \
  _Pragma("unroll") for (int mi = 0; mi < 8; ++mi)                                 \
  _Pragma("unroll") for (int ni = 0; ni < 4; ++ni)                                 \
    acc[mi][ni] = __builtin_amdgcn_mfma_f32_16x16x32_bf16(ak1[mi], b1[ni],         \
                                                          acc[mi][ni], 0, 0, 0);   \
  __builtin_amdgcn_s_setprio(0);                                                   \
  if ((VM) >= 0) {                                                                 \
    asm volatile("s_waitcnt lgkmcnt(0)" ::: "memory");                             \
    if ((VM) == 4)      asm volatile("s_waitcnt vmcnt(4)" ::: "memory");           \
    else                asm volatile("s_waitcnt vmcnt(0)" ::: "memory");           \
    __builtin_amdgcn_s_barrier();         /* END */                                \
  }                                                                                \
} while (0)

__global__ __launch_bounds__(512, 2) void gemm_bf16_fused(
    const unsigned short* __restrict__ A,
    const unsigned short* __restrict__ Bt,
    const float* __restrict__ gam, const float* __restrict__ bet,
    const float* __restrict__ mu, const float* __restrict__ var,
    float* __restrict__ C) {
  __shared__ __align__(16) unsigned short lds[65536];  // 128 KiB

  const int tid = threadIdx.x;
  const int wave = tid >> 6;
  const int lane = tid & 63;
  const int l15 = lane & 15, l4 = lane >> 4;
  const int wr = wave >> 2, wc = wave & 3;   // 2x4 wave grid; per-wave out 128x64

  // XCD-aware swizzle: 512 blocks, 512 % 8 == 0 -> bijective
  const int bid = (int)blockIdx.x;
  const int swz = (bid & 7) * 64 + (bid >> 3);
  const int bx = swz & 15;                   // 16 N-tiles
  const int by = swz >> 4;                   // 32 M-tiles
  const size_t bm = (size_t)by * 256;
  const size_t bn = (size_t)bx * 256;

  // stage source addresses (pre-swizzled global per lane; LDS dest linear)
  const int lr = lane >> 3, lc = lane & 7;
  const unsigned short* aS = A + (bm + (size_t)(wave * 8 + lr)) * K_DIM + (lc ^ lr) * 8;
  const unsigned short* bS = Bt + (bn + (size_t)(wave * 8 + lr)) * K_DIM + (lc ^ lr) * 8;

  // ds_read fragment offsets (u16 units); col8' = col8 ^ (row&7), row&7 == l15&7
  const int xk0 = ((l4)     ^ (l15 & 7)) * 8;
  const int xk1 = ((l4 | 4) ^ (l15 & 7)) * 8;
  const int aro = l15 * 64;
  const int bro = (wc & 1) * 4096 + l15 * 64;
  const int saW = wr * 8192;
  const int sbW = 32768 + (wc >> 1) * 8192;

  f32x4 acc[8][4] = {};

  // ---- prologue: stage A(0), B(0), B(1); wait A(0)+B(0) landed ----
  STG_A(0, 0, 1, -1); STG_A(0, 1, 1, -1);
  STG_A(1, 0, 1, -1); STG_A(1, 1, 1, -1);
  asm volatile("" ::: "memory");
  STG_B(0, 0, 0, -2); STG_B(0, 1, 0, -2);
  STG_B(1, 0, 0, -2); STG_B(1, 1, 0, -2);
  asm volatile("" ::: "memory");
  STG_B(0, 0, 1, -1); STG_B(0, 1, 1, -1);
  STG_B(1, 0, 1, -1); STG_B(1, 1, 1, -1);
  asm volatile("s_waitcnt vmcnt(4)" ::: "memory");
  __builtin_amdgcn_s_barrier();

  // ---- main loop: 64 K-tiles ----
  for (int t = 0; t < 60; t += 2) {
    KTILE(t,     0, 1, 1, 4);
    KTILE(t + 1, 1, 1, 1, 4);
  }
  KTILE(60, 0, 1, 1, 4);
  KTILE(61, 1, 1, 1, 4);   // stages A(62), B(63)
  KTILE(62, 0, 1, 0, 0);   // stages A(63); drain all outstanding
  KTILE(63, 1, 0, 0, -1);  // no stages, nothing outstanding, no end barrier

  // ---- epilogue: fused BN + GELU + ReLU ----
  const int row0 = (int)bm + wr * 128;
  const int col0 = (int)bn + wc * 64;
#pragma unroll
  for (int ni = 0; ni < 4; ++ni) {
    const int col = col0 + ni * 16 + l15;
    const float inv = rsqrtf(var[col] + EPS) * gam[col];
    const float shift = fmaf(-mu[col], inv, bet[col]);
#pragma unroll
    for (int mi = 0; mi < 8; ++mi) {
      const int r0 = row0 + mi * 16 + l4 * 4;
#pragma unroll
      for (int r = 0; r < 4; ++r)
        C[(size_t)(r0 + r) * N_DIM + col] = fused_epilogue(acc[mi][ni][r], inv, shift);
    }
  }
}

// ---------- fallback (only if ws too small): fp32 tiled GEMM ----------

__global__ __launch_bounds__(256) void gemm_f32_fallback(
    const float* __restrict__ A, const float* __restrict__ W,
    const float* __restrict__ gam, const float* __restrict__ bet,
    const float* __restrict__ mu, const float* __restrict__ var,
    float* __restrict__ C) {
  __shared__ float As[16][65];
  __shared__ float Bs[16][65];
  const int tid = threadIdx.x;
  const int tx = tid & 15, ty = tid >> 4;
  const int bn0 = blockIdx.x * 64, bm0 = blockIdx.y * 64;
  float acc[4][4] = {};
  for (int k0 = 0; k0 < K_DIM; k0 += 16) {
#pragma unroll
    for (int j = 0; j < 4; ++j)
      As[tid & 15][(tid >> 4) * 4 + j] =
          A[(size_t)(bm0 + (tid >> 4) * 4 + j) * K_DIM + k0 + (tid & 15)];
#pragma unroll
    for (int j = 0; j < 4; ++j)
      Bs[tid >> 4][(tid & 15) * 4 + j] =
          W[(size_t)(k0 + (tid >> 4)) * N_DIM + bn0 + (tid & 15) * 4 + j];
    __syncthreads();
#pragma unroll
    for (int kk = 0; kk < 16; ++kk) {
      float a_[4], b_[4];
#pragma unroll
      for (int i = 0; i < 4; ++i) a_[i] = As[kk][ty * 4 + i];
#pragma unroll
      for (int j = 0; j < 4; ++j) b_[j] = Bs[kk][tx * 4 + j];
#pragma unroll
      for (int i = 0; i < 4; ++i)
#pragma unroll
        for (int j = 0; j < 4; ++j)
          acc[i][j] = fmaf(a_[i], b_[j], acc[i][j]);
    }
    __syncthreads();
  }
#pragma unroll
  for (int j = 0; j < 4; ++j) {
    const int col = bn0 + tx * 4 + j;
    const float inv = rsqrtf(var[col] + EPS) * gam[col];
    const float shift = fmaf(-mu[col], inv, bet[col]);
#pragma unroll
    for (int i = 0; i < 4; ++i) {
      float y = fmaf(acc[i][j], inv, shift);
      float y2 = y * y;
      float z = fmaf(0.044715f * y2, y, y);
      float e = __builtin_amdgcn_exp2f(-2.3022081f * z);
      float ge = y * __builtin_amdgcn_rcpf(1.0f + e);
      C[(size_t)(bm0 + ty * 4 + i) * N_DIM + col] = fmaxf(ge, 0.0f);
    }
  }
}

// ---------- launch ----------

extern "C" void kernel_launch(void* const* d_in, const int* in_sizes, int n_in,
                              void* d_out, int out_size, void* d_ws, size_t ws_size,
                              hipStream_t stream) {
  const float* x  = (const float*)d_in[0];
  const float* w  = (const float*)d_in[1];
  const float* gg = (const float*)d_in[2];
  const float* bb = (const float*)d_in[3];
  const float* mu = (const float*)d_in[4];
  const float* vr = (const float*)d_in[5];
  float* out = (float*)d_out;

  const size_t xb_bytes = (size_t)M_DIM * K_DIM * 2;
  const size_t wt_bytes = (size_t)K_DIM * N_DIM * 2;

  if (ws_size >= xb_bytes + wt_bytes) {
    unsigned short* xb = (unsigned short*)d_ws;
    unsigned short* wt = xb + (size_t)M_DIM * K_DIM;
    cvt_x_kernel<<<dim3((M_DIM * (size_t)K_DIM) / 8 / 256), dim3(256), 0, stream>>>(x, xb);
    cvt_w_transpose<<<dim3(N_DIM / 32, K_DIM / 32), dim3(256), 0, stream>>>(w, wt);
    gemm_bf16_fused<<<dim3((M_DIM / 256) * (N_DIM / 256)), dim3(512), 0, stream>>>(
        xb, wt, gg, bb, mu, vr, out);
  } else {
    gemm_f32_fallback<<<dim3(N_DIM / 64, M_DIM / 64), dim3(256), 0, stream>>>(
        x, w, gg, bb, mu, vr, out);
  }
}